// Round 1
// baseline (258.841 us; speedup 1.0000x reference)
//
#include <hip/hip_runtime.h>

#define BB 8
#define NN 4096
#define CCH 512
#define KK 32
#define CLS 21
#define BN_EPS 1e-3f

#define TILE_R 32
#define XPAD 516          // 512 + 4: keeps float4 alignment, spreads rows across bank-quads
#define WPAD 36
#define CHUNK 128         // rows per block
#define NBLK (NN / CHUNK) // 32

// ws layout (floats)
#define WS_WX   0                     // 8*512*32 = 131072 floats
#define WS_WSUM (BB * CCH * KK)       // 256 floats
#define WS_ATTN (WS_WSUM + BB * KK)   // 4096 floats (16B-aligned: 131328*4 % 16 == 0)

// ---------------------------------------------------------------------------
// Kernel A: per-block (batch b, 128-row chunk) fused cross->softmax->wx partials
// ---------------------------------------------------------------------------
__global__ __launch_bounds__(256) void enc_partial(
    const float* __restrict__ x, const float* __restrict__ cw,
    const float* __restrict__ sf, float* __restrict__ ws)
{
    extern __shared__ float sm[];
    float* cwT  = sm;                      // [32][XPAD] fp32, transposed codewords
    float* xt   = sm + 32 * XPAD;          // [TILE_R][XPAD]
    float* wt   = sm + 64 * XPAD;          // [TILE_R][WPAD]
    float* cwsq = wt + TILE_R * WPAD;      // [32]
    float* red  = cwsq + 32;               // [4][32]

    const int t  = threadIdx.x;
    const int b  = blockIdx.y;
    const int cx = blockIdx.x;
    const int kq = t & 7;      // phase B/C: k = kq + 8*j  (stride-8 ownership)
    const int r  = t >> 3;     // phase B: row in tile; phase C: cgroup

    // ---- stage cwT (transpose) + codeword squared norms ----
    float sq0 = 0.f, sq1 = 0.f, sq2 = 0.f, sq3 = 0.f;
    {
        const int k4 = (t & 7) * 4;
        const int cb = t >> 3;
        for (int i = 0; i < 16; ++i) {
            const int c = 32 * i + cb;
            const float4 v = *reinterpret_cast<const float4*>(cw + c * KK + k4);
            cwT[(k4 + 0) * XPAD + c] = v.x;
            cwT[(k4 + 1) * XPAD + c] = v.y;
            cwT[(k4 + 2) * XPAD + c] = v.z;
            cwT[(k4 + 3) * XPAD + c] = v.w;
            sq0 += v.x * v.x; sq1 += v.y * v.y; sq2 += v.z * v.z; sq3 += v.w * v.w;
        }
        // reduce over c-parts (lane bits 3..5 within the wave)
        for (int off = 8; off <= 32; off <<= 1) {
            sq0 += __shfl_xor(sq0, off);
            sq1 += __shfl_xor(sq1, off);
            sq2 += __shfl_xor(sq2, off);
            sq3 += __shfl_xor(sq3, off);
        }
        if ((t & 63) < 8) {
            const int w = t >> 6;
            red[w * 32 + (t & 7) * 4 + 0] = sq0;
            red[w * 32 + (t & 7) * 4 + 1] = sq1;
            red[w * 32 + (t & 7) * 4 + 2] = sq2;
            red[w * 32 + (t & 7) * 4 + 3] = sq3;
        }
    }
    __syncthreads();
    if (t < 32) cwsq[t] = red[t] + red[32 + t] + red[64 + t] + red[96 + t];
    __syncthreads();

    // per-thread constants for its 4 k's
    float nsf[4], cq[4];
#pragma unroll
    for (int j = 0; j < 4; ++j) {
        nsf[j] = -sf[kq + 8 * j];
        cq[j]  = cwsq[kq + 8 * j];
    }

    float acc[16][4];
#pragma unroll
    for (int i = 0; i < 16; ++i)
#pragma unroll
        for (int j = 0; j < 4; ++j) acc[i][j] = 0.f;
    float wsacc[4] = {0.f, 0.f, 0.f, 0.f};

    const int n0base = cx * CHUNK;
    for (int tile = 0; tile < CHUNK / TILE_R; ++tile) {
        const int n0 = n0base + tile * TILE_R;
        // ---- phase A: stage x tile (coalesced global -> padded LDS) ----
        for (int i = 0; i < 16; ++i) {
            const int f   = i * 256 + t;
            const int rr  = f >> 7;
            const int cc4 = (f & 127) << 2;
            const float4 v = *reinterpret_cast<const float4*>(
                x + (size_t)(b * NN + n0 + rr) * CCH + cc4);
            *reinterpret_cast<float4*>(xt + rr * XPAD + cc4) = v;
        }
        __syncthreads();

        // ---- phase B1: x_sq for row r (c-part kq, reduce in-wave) ----
        float xs = 0.f;
        {
            const float* xr = xt + r * XPAD + kq * 64;
#pragma unroll 4
            for (int i = 0; i < 16; ++i) {
                const float4 v = *reinterpret_cast<const float4*>(xr + 4 * i);
                xs += v.x * v.x + v.y * v.y + v.z * v.z + v.w * v.w;
            }
            xs += __shfl_xor(xs, 1);
            xs += __shfl_xor(xs, 2);
            xs += __shfl_xor(xs, 4);
        }

        // ---- phase B2: cross[r][k] for k = kq+8j ----
        float cr[4] = {0.f, 0.f, 0.f, 0.f};
        {
            const float* xr = xt + r * XPAD;
#pragma unroll 2
            for (int c4 = 0; c4 < CCH; c4 += 4) {
                const float4 xv = *reinterpret_cast<const float4*>(xr + c4);
#pragma unroll
                for (int j = 0; j < 4; ++j) {
                    const float4 cv = *reinterpret_cast<const float4*>(
                        cwT + (kq + 8 * j) * XPAD + c4);
                    cr[j] += xv.x * cv.x + xv.y * cv.y + xv.z * cv.z + xv.w * cv.w;
                }
            }
        }

        // ---- phase B3: softmax over 32 k (4 local + 8 kq lanes) ----
        float l[4];
#pragma unroll
        for (int j = 0; j < 4; ++j) l[j] = (xs - 2.f * cr[j] + cq[j]) * nsf[j];
        float m = fmaxf(fmaxf(l[0], l[1]), fmaxf(l[2], l[3]));
        m = fmaxf(m, __shfl_xor(m, 1));
        m = fmaxf(m, __shfl_xor(m, 2));
        m = fmaxf(m, __shfl_xor(m, 4));
        float e[4];
        float s = 0.f;
#pragma unroll
        for (int j = 0; j < 4; ++j) { e[j] = expf(l[j] - m); s += e[j]; }
        s += __shfl_xor(s, 1);
        s += __shfl_xor(s, 2);
        s += __shfl_xor(s, 4);
        const float inv = 1.f / s;
#pragma unroll
        for (int j = 0; j < 4; ++j) {
            const float wv = e[j] * inv;
            wsacc[j] += wv;
            wt[r * WPAD + kq + 8 * j] = wv;
        }
        __syncthreads();

        // ---- phase C: wx[c][k] += w[n][k]*x[n][c], c = cgroup*16 + i ----
        {
            const int cb = (t >> 3) * 16;
#pragma unroll 2
            for (int rr = 0; rr < TILE_R; ++rr) {
                const float* wr = wt + rr * WPAD + kq;
                const float w0 = wr[0], w1 = wr[8], w2 = wr[16], w3 = wr[24];
                const float* xr = xt + rr * XPAD + cb;
#pragma unroll
                for (int i4 = 0; i4 < 4; ++i4) {
                    const float4 xv = *reinterpret_cast<const float4*>(xr + 4 * i4);
                    const float xa[4] = {xv.x, xv.y, xv.z, xv.w};
#pragma unroll
                    for (int q = 0; q < 4; ++q) {
                        acc[i4 * 4 + q][0] += xa[q] * w0;
                        acc[i4 * 4 + q][1] += xa[q] * w1;
                        acc[i4 * 4 + q][2] += xa[q] * w2;
                        acc[i4 * 4 + q][3] += xa[q] * w3;
                    }
                }
            }
        }
        __syncthreads();   // protect xt/wt before next tile's phase A
    }

    // ---- epilogue: combine partials ----
    {
        const int cb = (t >> 3) * 16;
        float* wx = ws + WS_WX;
        for (int i = 0; i < 16; ++i)
#pragma unroll
            for (int j = 0; j < 4; ++j)
                atomicAdd(&wx[(size_t)(b * CCH + cb + i) * KK + kq + 8 * j], acc[i][j]);
    }
#pragma unroll
    for (int j = 0; j < 4; ++j) {
        float v = wsacc[j];
        v += __shfl_xor(v, 8);
        v += __shfl_xor(v, 16);
        v += __shfl_xor(v, 32);
        if ((t & 63) < 8) atomicAdd(&ws[WS_WSUM + b * KK + kq + 8 * j], v);
    }
}

// ---------------------------------------------------------------------------
// Kernel B: enc -> BN -> ReLU -> sum_k -> attn sigmoid + se_loss sigmoid
// ---------------------------------------------------------------------------
__global__ __launch_bounds__(256) void finalize_kernel(
    float* __restrict__ ws, const float* __restrict__ cw,
    const float* __restrict__ gamma, const float* __restrict__ beta,
    const float* __restrict__ mean, const float* __restrict__ var,
    const float* __restrict__ w_enc, const float* __restrict__ b_enc,
    const float* __restrict__ w_se, const float* __restrict__ b_se,
    float* __restrict__ out)
{
    __shared__ float encv[CCH];
    __shared__ float wsum_s[KK];
    const int b = blockIdx.x;
    const int t = threadIdx.x;

    if (t < KK) wsum_s[t] = ws[WS_WSUM + b * KK + t];
    __syncthreads();

    for (int c = t; c < CCH; c += 256) {
        const float g  = gamma[c] * rsqrtf(var[c] + BN_EPS);
        const float mu = mean[c];
        const float be = beta[c];
        const float* wxr = ws + WS_WX + (size_t)(b * CCH + c) * KK;
        const float* cwr = cw + c * KK;
        float s = 0.f;
#pragma unroll 8
        for (int k = 0; k < KK; ++k) {
            const float enc = wxr[k] - cwr[k] * wsum_s[k];
            const float v   = (enc - mu) * g + be;
            s += fmaxf(v, 0.f);
        }
        encv[c] = s;
    }
    __syncthreads();

    // attn over C outputs
    for (int c2 = t; c2 < CCH; c2 += 256) {
        float a = b_enc[c2];
#pragma unroll 4
        for (int c = 0; c < CCH; ++c) a += encv[c] * w_enc[c * CCH + c2];
        ws[WS_ATTN + b * CCH + c2] = 1.f / (1.f + expf(-a));
    }

    // se_loss: 21 classes, 8 lanes each
    if (t < 8 * CLS) {
        const int j = t >> 3, p = t & 7;
        float a = 0.f;
        for (int c = p; c < CCH; c += 8) a += encv[c] * w_se[c * CLS + j];
        a += __shfl_xor(a, 1);
        a += __shfl_xor(a, 2);
        a += __shfl_xor(a, 4);
        if (p == 0)
            out[(size_t)BB * NN * CCH + b * CLS + j] =
                1.f / (1.f + expf(-(a + b_se[j])));
    }
}

// ---------------------------------------------------------------------------
// Kernel C: featuremaps = attn[b,c] * x
// ---------------------------------------------------------------------------
__global__ __launch_bounds__(256) void scale_out(
    const float* __restrict__ x, const float* __restrict__ ws,
    float* __restrict__ out)
{
    const int gid = blockIdx.x * 256 + threadIdx.x;   // 0 .. 524287 (f4 per batch)
    const int c4  = (gid & 127) << 2;
#pragma unroll
    for (int b = 0; b < BB; ++b) {
        const size_t f = ((size_t)b << 19) + (size_t)gid;
        const float4 xv = *reinterpret_cast<const float4*>(x + 4 * f);
        const float4 av = *reinterpret_cast<const float4*>(ws + WS_ATTN + b * CCH + c4);
        float4 o;
        o.x = xv.x * av.x; o.y = xv.y * av.y; o.z = xv.z * av.z; o.w = xv.w * av.w;
        *reinterpret_cast<float4*>(out + 4 * f) = o;
    }
}

// ---------------------------------------------------------------------------
extern "C" void kernel_launch(void* const* d_in, const int* in_sizes, int n_in,
                              void* d_out, int out_size, void* d_ws, size_t ws_size,
                              hipStream_t stream)
{
    const float* x     = (const float*)d_in[0];
    const float* cw    = (const float*)d_in[1];
    const float* sf    = (const float*)d_in[2];
    const float* gamma = (const float*)d_in[3];
    const float* beta  = (const float*)d_in[4];
    const float* mean  = (const float*)d_in[5];
    const float* var   = (const float*)d_in[6];
    const float* w_enc = (const float*)d_in[7];
    const float* b_enc = (const float*)d_in[8];
    const float* w_se  = (const float*)d_in[9];
    const float* b_se  = (const float*)d_in[10];
    float* out = (float*)d_out;
    float* ws  = (float*)d_ws;

    hipMemsetAsync(d_ws, 0, (size_t)(BB * CCH * KK + BB * KK) * sizeof(float), stream);

    const size_t shmem =
        (size_t)(64 * XPAD + TILE_R * WPAD + 32 + 128) * sizeof(float);
    enc_partial<<<dim3(NBLK, BB), 256, shmem, stream>>>(x, cw, sf, ws);
    finalize_kernel<<<BB, 256, 0, stream>>>(ws, cw, gamma, beta, mean, var,
                                            w_enc, b_enc, w_se, b_se, out);
    scale_out<<<2048, 256, 0, stream>>>(x, ws, out);
}

// Round 2
// 208.487 us; speedup vs baseline: 1.2415x; 1.2415x over previous
//
#include <hip/hip_runtime.h>

#define BB 8
#define NN 4096
#define CCH 512
#define KK 32
#define CLS 21
#define BN_EPS 1e-3f

#define TPB 512
#define TILE_R 32
#define XPAD 520          // 512+8: rows shift 8 banks; float4-aligned
#define WPAD 36
#define CHUNK 128
#define NBLK (NN / CHUNK) // 32

// shared-memory carve (floats)
#define SM_CWT 0
#define SM_XT  (KK * XPAD)                 // 16640
#define SM_WT  (SM_XT + TILE_R * XPAD)     // 33280
#define SM_CSQ (SM_WT + TILE_R * WPAD)     // 34432
#define SM_TOT (SM_CSQ + KK)               // 34464 floats = 137856 B

// ws layout (floats)
#define WS_WX   0
#define WS_WSUM (BB * CCH * KK)            // 131072
#define WS_ENC  (WS_WSUM + BB * KK)        // 131328
#define WS_ATTN (WS_ENC + BB * CCH)        // 135424

template <int CTRL>
__device__ __forceinline__ float dpp_add(float v) {
    int r = __builtin_amdgcn_update_dpp(0, __builtin_bit_cast(int, v),
                                        CTRL, 0xF, 0xF, true);
    return v + __builtin_bit_cast(float, r);
}
// full sum across the 16-lane DPP row via rotations (commutative): all lanes get total
__device__ __forceinline__ float rowsum16(float v) {
    v = dpp_add<0x128>(v);  // row_ror:8
    v = dpp_add<0x124>(v);  // row_ror:4
    v = dpp_add<0x122>(v);  // row_ror:2
    v = dpp_add<0x121>(v);  // row_ror:1
    return v;
}

__device__ __forceinline__ float dot4(const float4 a, const float4 b) {
    return a.x * b.x + a.y * b.y + a.z * b.z + a.w * b.w;
}

// ---------------------------------------------------------------------------
// Kernel A: fused cross -> softmax -> wx partials.  512 thr, 1 block/CU.
// B2 thread map: cpart = t&15 (c-slice), kg = (t>>4)&3 (k = kg+4j), rg = t>>6 (rows rg*4+q)
// C  thread map: kq = t&7 (k = kq*4+j), cg = (t>>3)&31 (c = cg*16+i), rp = t>>8 (rows rp*16+rr)
// ---------------------------------------------------------------------------
__global__ __launch_bounds__(TPB, 2) void enc_partial(
    const float* __restrict__ x, const float* __restrict__ cw,
    const float* __restrict__ sf, float* __restrict__ ws)
{
    extern __shared__ float sm[];
    const int t = threadIdx.x;
    const int b = blockIdx.y;

    // ---- stage cwT (transposed codewords) ----
    {
        const int c0 = t >> 3;
        const int k4 = (t & 7) * 4;
        for (int i = 0; i < 8; ++i) {
            const int c = i * 64 + c0;
            const float4 v = *reinterpret_cast<const float4*>(cw + c * KK + k4);
            sm[SM_CWT + (k4 + 0) * XPAD + c] = v.x;
            sm[SM_CWT + (k4 + 1) * XPAD + c] = v.y;
            sm[SM_CWT + (k4 + 2) * XPAD + c] = v.z;
            sm[SM_CWT + (k4 + 3) * XPAD + c] = v.w;
        }
    }
    __syncthreads();
    if (t < KK) {
        float s = 0.f;
        const float* r = sm + SM_CWT + t * XPAD;
        for (int c = 0; c < CCH; c += 4) {
            const float4 v = *reinterpret_cast<const float4*>(r + c);
            s += v.x * v.x + v.y * v.y + v.z * v.z + v.w * v.w;
        }
        sm[SM_CSQ + t] = s;
    }
    __syncthreads();

    const int cpart = t & 15;
    const int kg    = (t >> 4) & 3;
    const int rg    = t >> 6;
    float nsf[8], cq[8];
#pragma unroll
    for (int j = 0; j < 8; ++j) {
        const int k = kg + 4 * j;
        nsf[j] = -sf[k];
        cq[j]  = sm[SM_CSQ + k];
    }

    const int kq = t & 7;
    const int cg = (t >> 3) & 31;
    const int rp = t >> 8;

    float acc[16][4];
#pragma unroll
    for (int i = 0; i < 16; ++i)
#pragma unroll
        for (int j = 0; j < 4; ++j) acc[i][j] = 0.f;
    float wsacc[8] = {0.f, 0.f, 0.f, 0.f, 0.f, 0.f, 0.f, 0.f};

    const int n0base = blockIdx.x * CHUNK;
    for (int tile = 0; tile < CHUNK / TILE_R; ++tile) {
        const int n0 = n0base + tile * TILE_R;
        // ---- stage x tile ----
        for (int i = 0; i < 8; ++i) {
            const int f  = i * TPB + t;
            const int rr = f >> 7;
            const int c4 = (f & 127) << 2;
            const float4 v = *reinterpret_cast<const float4*>(
                x + (size_t)(b * NN + n0 + rr) * CCH + c4);
            *reinterpret_cast<float4*>(sm + SM_XT + rr * XPAD + c4) = v;
        }
        __syncthreads();

        // ---- B2: cross partials over c-slice, register-tiled 4 rows x 8 k ----
        float cr[4][8];
        float xs[4] = {0.f, 0.f, 0.f, 0.f};
#pragma unroll
        for (int q = 0; q < 4; ++q)
#pragma unroll
            for (int j = 0; j < 8; ++j) cr[q][j] = 0.f;

#pragma unroll 2
        for (int s = 0; s < 8; ++s) {
            const int c4 = cpart * 4 + s * 64;
            float4 xv[4];
#pragma unroll
            for (int q = 0; q < 4; ++q) {
                xv[q] = *reinterpret_cast<const float4*>(
                    sm + SM_XT + (rg * 4 + q) * XPAD + c4);
                xs[q] += dot4(xv[q], xv[q]);
            }
#pragma unroll
            for (int j = 0; j < 8; ++j) {
                const float4 cv = *reinterpret_cast<const float4*>(
                    sm + SM_CWT + (kg + 4 * j) * XPAD + c4);
#pragma unroll
                for (int q = 0; q < 4; ++q) cr[q][j] += dot4(xv[q], cv);
            }
        }
        // reduce over the 16 cpart lanes (DPP row = exactly the cpart group)
#pragma unroll
        for (int q = 0; q < 4; ++q) xs[q] = rowsum16(xs[q]);
#pragma unroll
        for (int q = 0; q < 4; ++q)
#pragma unroll
            for (int j = 0; j < 8; ++j) cr[q][j] = rowsum16(cr[q][j]);

        // ---- softmax over 32 k (8 local j + 4 kg lanes via xor16/32) ----
        float w[4][8];
#pragma unroll
        for (int q = 0; q < 4; ++q) {
            float l[8];
#pragma unroll
            for (int j = 0; j < 8; ++j)
                l[j] = (xs[q] - 2.f * cr[q][j] + cq[j]) * nsf[j];
            float m = l[0];
#pragma unroll
            for (int j = 1; j < 8; ++j) m = fmaxf(m, l[j]);
            m = fmaxf(m, __shfl_xor(m, 16));
            m = fmaxf(m, __shfl_xor(m, 32));
            float ssum = 0.f;
#pragma unroll
            for (int j = 0; j < 8; ++j) { w[q][j] = __expf(l[j] - m); ssum += w[q][j]; }
            ssum += __shfl_xor(ssum, 16);
            ssum += __shfl_xor(ssum, 32);
            const float inv = 1.f / ssum;
#pragma unroll
            for (int j = 0; j < 8; ++j) w[q][j] *= inv;
        }
        if (cpart == 0) {
#pragma unroll
            for (int q = 0; q < 4; ++q)
#pragma unroll
                for (int j = 0; j < 8; ++j) {
                    sm[SM_WT + (rg * 4 + q) * WPAD + kg + 4 * j] = w[q][j];
                    wsacc[j] += w[q][j];
                }
        }
        __syncthreads();   // wt ready

        // ---- C: wx[c][k] accumulation, 16 c x 4 contiguous k per thread ----
#pragma unroll 2
        for (int rr0 = 0; rr0 < 16; ++rr0) {
            const int rr = rp * 16 + rr0;
            const float4 wv = *reinterpret_cast<const float4*>(
                sm + SM_WT + rr * WPAD + kq * 4);
            const float* xr = sm + SM_XT + rr * XPAD + cg * 16;
#pragma unroll
            for (int i4 = 0; i4 < 4; ++i4) {
                const float4 xv = *reinterpret_cast<const float4*>(xr + i4 * 4);
                const float xa[4] = {xv.x, xv.y, xv.z, xv.w};
#pragma unroll
                for (int p = 0; p < 4; ++p) {
                    acc[i4 * 4 + p][0] += xa[p] * wv.x;
                    acc[i4 * 4 + p][1] += xa[p] * wv.y;
                    acc[i4 * 4 + p][2] += xa[p] * wv.z;
                    acc[i4 * 4 + p][3] += xa[p] * wv.w;
                }
            }
        }
        __syncthreads();   // protect xt/wt before next stage
    }

    // ---- combine rp pairs in LDS (stride 68 = 17 float4 to avoid bank alias) ----
    if (rp == 1) {
        float* d = sm + (t & 255) * 68;
#pragma unroll
        for (int i = 0; i < 16; ++i)
            *reinterpret_cast<float4*>(d + i * 4) =
                make_float4(acc[i][0], acc[i][1], acc[i][2], acc[i][3]);
    }
    __syncthreads();
    if (rp == 0) {
        const float* s_ = sm + t * 68;
#pragma unroll
        for (int i = 0; i < 16; ++i) {
            const float4 v = *reinterpret_cast<const float4*>(s_ + i * 4);
            acc[i][0] += v.x; acc[i][1] += v.y; acc[i][2] += v.z; acc[i][3] += v.w;
        }
        float* wx = ws + WS_WX + (size_t)b * CCH * KK;
        for (int i = 0; i < 16; ++i)
#pragma unroll
            for (int j = 0; j < 4; ++j)
                atomicAdd(&wx[(cg * 16 + i) * KK + kq * 4 + j], acc[i][j]);
    }
    if (cpart == 0) {
#pragma unroll
        for (int j = 0; j < 8; ++j)
            atomicAdd(&ws[WS_WSUM + b * KK + kg + 4 * j], wsacc[j]);
    }
}

// ---------------------------------------------------------------------------
// Kernel B1: enc -> BN -> ReLU -> sum_k  => encv[b][c]
// ---------------------------------------------------------------------------
__global__ __launch_bounds__(256) void encv_kernel(
    float* __restrict__ ws, const float* __restrict__ cw,
    const float* __restrict__ gamma, const float* __restrict__ beta,
    const float* __restrict__ mean, const float* __restrict__ var)
{
    __shared__ float wsum_s[KK];
    const int b = blockIdx.x;
    const int t = threadIdx.x;
    if (t < KK) wsum_s[t] = ws[WS_WSUM + b * KK + t];
    __syncthreads();
    for (int c = t; c < CCH; c += 256) {
        const float g  = gamma[c] * rsqrtf(var[c] + BN_EPS);
        const float mu = mean[c];
        const float be = beta[c];
        const float* wxr = ws + WS_WX + (size_t)(b * CCH + c) * KK;
        const float* cwr = cw + c * KK;
        float s = 0.f;
#pragma unroll
        for (int k4 = 0; k4 < KK; k4 += 4) {
            const float4 wv = *reinterpret_cast<const float4*>(wxr + k4);
            const float4 cv = *reinterpret_cast<const float4*>(cwr + k4);
            const float4 sv = *reinterpret_cast<const float4*>(&wsum_s[k4]);
            s += fmaxf((wv.x - cv.x * sv.x - mu) * g + be, 0.f);
            s += fmaxf((wv.y - cv.y * sv.y - mu) * g + be, 0.f);
            s += fmaxf((wv.z - cv.z * sv.z - mu) * g + be, 0.f);
            s += fmaxf((wv.w - cv.w * sv.w - mu) * g + be, 0.f);
        }
        ws[WS_ENC + b * CCH + c] = s;
    }
}

// ---------------------------------------------------------------------------
// Kernel B2: attn = sigmoid(encv @ w_enc + b_enc) ; se = sigmoid(encv @ w_se + b_se)
// grid (9, B): cgb 0..7 attn 64-col chunks, cgb==8 se
// ---------------------------------------------------------------------------
__global__ __launch_bounds__(256) void attn_se_kernel(
    float* __restrict__ ws, const float* __restrict__ w_enc,
    const float* __restrict__ b_enc, const float* __restrict__ w_se,
    const float* __restrict__ b_se, float* __restrict__ out)
{
    __shared__ float ev[CCH];
    __shared__ float red[4][64];
    const int b   = blockIdx.y;
    const int cgb = blockIdx.x;
    const int t   = threadIdx.x;
    ev[t]       = ws[WS_ENC + b * CCH + t];
    ev[t + 256] = ws[WS_ENC + b * CCH + 256 + t];
    __syncthreads();
    if (cgb < 8) {
        const int c2 = cgb * 64 + (t & 63);
        const int p  = t >> 6;
        float a = 0.f;
#pragma unroll 4
        for (int i = 0; i < 128; ++i) {
            const int c = p * 128 + i;
            a += ev[c] * w_enc[c * CCH + c2];
        }
        red[p][t & 63] = a;
        __syncthreads();
        if (t < 64) {
            const float v = red[0][t] + red[1][t] + red[2][t] + red[3][t]
                          + b_enc[cgb * 64 + t];
            ws[WS_ATTN + b * CCH + cgb * 64 + t] = 1.f / (1.f + __expf(-v));
        }
    } else if (t < 8 * CLS) {
        const int j = t >> 3, p = t & 7;
        float a = 0.f;
        for (int c = p; c < CCH; c += 8) a += ev[c] * w_se[c * CLS + j];
        a += __shfl_xor(a, 1);
        a += __shfl_xor(a, 2);
        a += __shfl_xor(a, 4);
        if (p == 0)
            out[(size_t)BB * NN * CCH + b * CLS + j] =
                1.f / (1.f + __expf(-(a + b_se[j])));
    }
}

// ---------------------------------------------------------------------------
// Kernel C: featuremaps = attn[b,c] * x
// ---------------------------------------------------------------------------
__global__ __launch_bounds__(256) void scale_out(
    const float* __restrict__ x, const float* __restrict__ ws,
    float* __restrict__ out)
{
    const int gid = blockIdx.x * 256 + threadIdx.x;
    const int c4  = (gid & 127) << 2;
#pragma unroll
    for (int b = 0; b < BB; ++b) {
        const size_t f = ((size_t)b << 19) + (size_t)gid;
        const float4 xv = *reinterpret_cast<const float4*>(x + 4 * f);
        const float4 av = *reinterpret_cast<const float4*>(ws + WS_ATTN + b * CCH + c4);
        float4 o;
        o.x = xv.x * av.x; o.y = xv.y * av.y; o.z = xv.z * av.z; o.w = xv.w * av.w;
        *reinterpret_cast<float4*>(out + 4 * f) = o;
    }
}

// ---------------------------------------------------------------------------
extern "C" void kernel_launch(void* const* d_in, const int* in_sizes, int n_in,
                              void* d_out, int out_size, void* d_ws, size_t ws_size,
                              hipStream_t stream)
{
    const float* x     = (const float*)d_in[0];
    const float* cw    = (const float*)d_in[1];
    const float* sf    = (const float*)d_in[2];
    const float* gamma = (const float*)d_in[3];
    const float* beta  = (const float*)d_in[4];
    const float* mean  = (const float*)d_in[5];
    const float* var   = (const float*)d_in[6];
    const float* w_enc = (const float*)d_in[7];
    const float* b_enc = (const float*)d_in[8];
    const float* w_se  = (const float*)d_in[9];
    const float* b_se  = (const float*)d_in[10];
    float* out = (float*)d_out;
    float* ws  = (float*)d_ws;

    hipMemsetAsync(d_ws, 0, (size_t)(WS_WSUM + BB * KK) * sizeof(float), stream);

    enc_partial<<<dim3(NBLK, BB), TPB, SM_TOT * sizeof(float), stream>>>(x, cw, sf, ws);
    encv_kernel<<<BB, 256, 0, stream>>>(ws, cw, gamma, beta, mean, var);
    attn_se_kernel<<<dim3(9, BB), 256, 0, stream>>>(ws, w_enc, b_enc, w_se, b_se, out);
    scale_out<<<2048, 256, 0, stream>>>(x, ws, out);
}